// Round 2
// baseline (139.632 us; speedup 1.0000x reference)
//
#include <hip/hip_runtime.h>

// Problem constants (from reference): B=64, OH=120, OW=160, THRESHOLD=0.5
#define OW_   160
#define OH_   120
#define HW_   (OH_ * OW_)          // 19200
#define BATCH 64
#define NPIX  (BATCH * HW_)        // 1228800
#define BLK   256
#define PPT   2                    // pixels per thread (float2 path)
#define TILE  (BLK * PPT)          // 512 pixels per block

// Output layout in d_out (flat, return order):
//   boxes     [NPIX*5]   at offset 0
//   landmarks [NPIX*10]  at offset NPIX*5
//   keep      [NPIX]     at offset NPIX*15
#define LM_OFF   ((size_t)NPIX * 5)
#define KEEP_OFF ((size_t)NPIX * 15)

// Notes on index math: TILE=512 divides HW_=19200, and each thread's 2 pixels
// are consecutive with even base -> never cross a batch boundary; OW_=160 is
// even -> both pixels share the same heatmap row h. float2 loads are 8B-aligned.

__global__ __launch_bounds__(BLK) void detpost_kernel(
    const float* __restrict__ heatmap,   // [B,1,H,W]
    const float* __restrict__ scale,     // [B,2,H,W]
    const float* __restrict__ offset,    // [B,2,H,W]
    const float* __restrict__ landmark,  // [B,10,H,W]
    float* __restrict__ boxes,           // [B*HW,5]
    float* __restrict__ lms,             // [B*HW,10]
    float* __restrict__ keepo)           // [B*HW]
{
    __shared__ float sbox[TILE * 5];     // 10 KB
    __shared__ float slm [TILE * 10];    // 20 KB

    const int tid  = threadIdx.x;
    const int idx  = blockIdx.x * TILE + tid * PPT;  // first pixel (even)
    const int b    = idx / HW_;
    const int p    = idx - b * HW_;
    const int h    = p / OW_;                        // shared by both pixels

    // ---- coalesced float2 channel-planar loads (8B/lane) ----
    const float2 sv  = *(const float2*)(heatmap + idx);
    const float* scb = scale  + (size_t)b * 2 * HW_;
    const float2 sc0 = *(const float2*)(scb + p);
    const float2 sc1 = *(const float2*)(scb + HW_ + p);
    const float2 of0 = *(const float2*)(offset + (size_t)b * 2 * HW_ + p);

    const float hb = (float)h + 0.5f;

    float e0v[PPT], e1v[PPT], y1v[PPT], x1v[PPT];
    bool  kv[PPT];

#pragma unroll
    for (int k = 0; k < PPT; ++k) {
        const float c0 = k ? sc0.y : sc0.x;
        const float c1 = k ? sc1.y : sc1.x;
        const float o0 = k ? of0.y : of0.x;
        const float sc = k ? sv.y  : sv.x;

        const float e0 = __expf(c0) * 4.0f;
        const float e1 = __expf(c1) * 4.0f;
        const float y1raw = (hb + o0) * 4.0f - e0 * 0.5f;
        const float y1c = fmaxf(y1raw, 0.0f);
        const float y1  = fminf(y1c, 480.0f);   // in_h = OH*4
        const float x1  = fminf(y1c, 640.0f);   // in_w = OW*4 (from y1c — reference quirk)
        const float y2  = fminf(y1 + e0, 480.0f);
        const float x2  = fminf(x1 + e1, 640.0f);
        const bool keep = (sc >= 0.5f);

        float* bb = sbox + (tid * PPT + k) * 5;
        bb[0] = keep ? x1 : 0.0f;
        bb[1] = keep ? y1 : 0.0f;
        bb[2] = keep ? x2 : 0.0f;
        bb[3] = keep ? y2 : 0.0f;
        bb[4] = keep ? sc : 0.0f;

        e0v[k] = e0; e1v[k] = e1; y1v[k] = y1; x1v[k] = x1; kv[k] = keep;
    }

    // keep mask is output-linear already: direct coalesced float2 store
    {
        float2 kk;
        kk.x = kv[0] ? 1.0f : 0.0f;
        kk.y = kv[1] ? 1.0f : 0.0f;
        *(float2*)(keepo + idx) = kk;
    }

    // ---- landmarks: even channels use (e0,y1), odd use (e1,x1) ----
    const float* lmb = landmark + (size_t)b * 10 * HW_ + p;
#pragma unroll
    for (int c = 0; c < 10; ++c) {
        const float2 lv = *(const float2*)(lmb + (size_t)c * HW_);
        const float m0 = (c & 1) ? fmaf(lv.x, e1v[0], x1v[0]) : fmaf(lv.x, e0v[0], y1v[0]);
        const float m1 = (c & 1) ? fmaf(lv.y, e1v[1], x1v[1]) : fmaf(lv.y, e0v[1], y1v[1]);
        slm[(tid * PPT + 0) * 10 + c] = kv[0] ? m0 : 0.0f;
        slm[(tid * PPT + 1) * 10 + c] = kv[1] ? m1 : 0.0f;
    }

    __syncthreads();

    // ---- coalesced float4 stores from LDS (output-linear) ----
    {
        const float4* sb4 = (const float4*)sbox;
        float4* gb4 = (float4*)(boxes + (size_t)blockIdx.x * (TILE * 5));
#pragma unroll
        for (int j = tid; j < TILE * 5 / 4; j += BLK) gb4[j] = sb4[j];   // 640 vecs
    }
    {
        const float4* sl4 = (const float4*)slm;
        float4* gl4 = (float4*)(lms + (size_t)blockIdx.x * (TILE * 10));
#pragma unroll
        for (int j = tid; j < TILE * 10 / 4; j += BLK) gl4[j] = sl4[j];  // 1280 vecs
    }
}

extern "C" void kernel_launch(void* const* d_in, const int* in_sizes, int n_in,
                              void* d_out, int out_size, void* d_ws, size_t ws_size,
                              hipStream_t stream) {
    const float* heatmap  = (const float*)d_in[0];
    const float* scale    = (const float*)d_in[1];
    const float* offset   = (const float*)d_in[2];
    const float* landmark = (const float*)d_in[3];

    float* out   = (float*)d_out;
    float* boxes = out;
    float* lms   = out + LM_OFF;
    float* keepo = out + KEEP_OFF;

    const int nblocks = NPIX / TILE;   // 2400, exact
    detpost_kernel<<<nblocks, BLK, 0, stream>>>(heatmap, scale, offset, landmark,
                                                boxes, lms, keepo);
}